// Round 3
// baseline (5263.137 us; speedup 1.0000x reference)
//
#include <hip/hip_runtime.h>
#include <hip/hip_bf16.h>
#include <math.h>

// ---------------- constants ----------------
#define NN 3600      // nodes
#define HIMG 300
#define WIMG 300
#define NHP 60       // patches per side

__device__ __forceinline__ float bf2f(unsigned short u) {
  union { unsigned int i; float f; } v; v.i = ((unsigned int)u) << 16; return v.f;
}
// mode: 1 = buffers are bf16, 0 = buffers are f32
__device__ __forceinline__ float ldE(const void* p, long i, int md) {
  return md ? bf2f(((const unsigned short*)p)[i]) : ((const float*)p)[i];
}

// ---------------- dtype detector ----------------
// bf16 N(0,1) data: exponent field always < 0x90. f32 data: low halves are
// ~uniform bits -> exponent field >= 0x90 with p~0.44 per element.
__global__ void detect_mode(const unsigned short* __restrict__ x, int* __restrict__ flag) {
  if (threadIdx.x == 0 && blockIdx.x == 0) {
    int bad = 0;
    for (int i = 0; i < 8192; ++i) {
      int e = (x[i] >> 7) & 0xFF;
      if (e >= 0x90) bad = 1;
    }
    flag[0] = bad ? 0 : 1;
  }
}

// ---------------- patch-embed GEMM: emb1 = relu(patches @ W1^T + b1) ----------------
__global__ __launch_bounds__(256) void patch_gemm(
    const void* __restrict__ x, const void* __restrict__ w,
    const void* __restrict__ bias, float* __restrict__ out, const int* __restrict__ mode) {
  const int md = *mode;
  __shared__ float As[25][64];
  __shared__ float Bs[25][64];
  const int m0 = blockIdx.y * 64, n0 = blockIdx.x * 64;
  const int tid = threadIdx.x;
  const int tr = tid >> 4, tc = tid & 15;
  float acc[4][4];
#pragma unroll
  for (int i = 0; i < 4; ++i)
#pragma unroll
    for (int j = 0; j < 4; ++j) acc[i][j] = 0.f;

  for (int c = 0; c < 256; ++c) {
    __syncthreads();
    for (int e = tid; e < 1600; e += 256) {
      int p = e / 25, q = e - p * 25;
      int ki = q / 5, li = q - ki * 5;
      int n = m0 + p;
      float v = 0.f;
      if (n < NN) {
        int ni = n / NHP, nj = n - ni * NHP;
        v = ldE(x, (long)c * (HIMG * WIMG) + (5 * ni + ki) * WIMG + 5 * nj + li, md);
      }
      As[q][p] = v;
    }
    for (int e = tid; e < 1600; e += 256) {
      int o = e / 25, q = e - o * 25;
      Bs[q][o] = ldE(w, (long)(n0 + o) * 6400 + c * 25 + q, md);
    }
    __syncthreads();
#pragma unroll
    for (int kk = 0; kk < 25; ++kk) {
      float a[4], b[4];
#pragma unroll
      for (int i = 0; i < 4; ++i) a[i] = As[kk][tr * 4 + i];
#pragma unroll
      for (int j = 0; j < 4; ++j) b[j] = Bs[kk][tc * 4 + j];
#pragma unroll
      for (int i = 0; i < 4; ++i)
#pragma unroll
        for (int j = 0; j < 4; ++j) acc[i][j] = fmaf(a[i], b[j], acc[i][j]);
    }
  }
#pragma unroll
  for (int i = 0; i < 4; ++i) {
    int row = m0 + tr * 4 + i;
    if (row < NN) {
#pragma unroll
      for (int j = 0; j < 4; ++j) {
        int col = n0 + tc * 4 + j;
        float v = acc[i][j] + ldE(bias, col, md);
        out[(size_t)row * 256 + col] = fmaxf(v, 0.f);
      }
    }
  }
}

// ---------------- generic GEMM: C[M,N] = act(A @ B[boff..](ldb) + bias) ----------------
// ACT: 0 none, 1 relu.  ACC: 0 store (with bias), 1 accumulate into C (no bias).
template <int ACT, int ACC>
__global__ __launch_bounds__(256) void gemm_aw(
    const float* __restrict__ A, const void* __restrict__ B, long boff,
    const void* __restrict__ bias, long biasoff, float* __restrict__ C,
    int M, int K, int ldb, const int* __restrict__ mode) {
  const int md = *mode;
  __shared__ float As[16][64];
  __shared__ float Bs[16][64];
  const int m0 = blockIdx.y * 64, n0 = blockIdx.x * 64;
  const int tid = threadIdx.x;
  const int tr = tid >> 4, tc = tid & 15;
  float acc[4][4];
#pragma unroll
  for (int i = 0; i < 4; ++i)
#pragma unroll
    for (int j = 0; j < 4; ++j) acc[i][j] = 0.f;

  for (int k0 = 0; k0 < K; k0 += 16) {
    __syncthreads();
    {
      int r = tid >> 2, kq = tid & 3;
      int row = m0 + r;
      float4 v = make_float4(0.f, 0.f, 0.f, 0.f);
      if (row < M) v = *(const float4*)(A + (size_t)row * K + k0 + kq * 4);
      As[kq * 4 + 0][r] = v.x;
      As[kq * 4 + 1][r] = v.y;
      As[kq * 4 + 2][r] = v.z;
      As[kq * 4 + 3][r] = v.w;
    }
    {
      int kr = tid >> 4, nc = tid & 15;
      long bidx = (long)(k0 + kr) * ldb + boff + n0 + nc * 4;
      if (md) {
        const unsigned short* bp = (const unsigned short*)B + bidx;
        Bs[kr][nc * 4 + 0] = bf2f(bp[0]);
        Bs[kr][nc * 4 + 1] = bf2f(bp[1]);
        Bs[kr][nc * 4 + 2] = bf2f(bp[2]);
        Bs[kr][nc * 4 + 3] = bf2f(bp[3]);
      } else {
        const float* bp = (const float*)B + bidx;
        Bs[kr][nc * 4 + 0] = bp[0];
        Bs[kr][nc * 4 + 1] = bp[1];
        Bs[kr][nc * 4 + 2] = bp[2];
        Bs[kr][nc * 4 + 3] = bp[3];
      }
    }
    __syncthreads();
#pragma unroll
    for (int kk = 0; kk < 16; ++kk) {
      float a[4], b[4];
#pragma unroll
      for (int i = 0; i < 4; ++i) a[i] = As[kk][tr * 4 + i];
#pragma unroll
      for (int j = 0; j < 4; ++j) b[j] = Bs[kk][tc * 4 + j];
#pragma unroll
      for (int i = 0; i < 4; ++i)
#pragma unroll
        for (int j = 0; j < 4; ++j) acc[i][j] = fmaf(a[i], b[j], acc[i][j]);
    }
  }
#pragma unroll
  for (int i = 0; i < 4; ++i) {
    int row = m0 + tr * 4 + i;
    if (row < M) {
#pragma unroll
      for (int j = 0; j < 4; ++j) {
        int col = n0 + tc * 4 + j;
        float v;
        if (ACC == 1) {
          v = C[(size_t)row * 256 + col] + acc[i][j];
        } else {
          v = acc[i][j] + ldE(bias, biasoff + col, md);
          if (ACT == 1) v = fmaxf(v, 0.f);
        }
        C[(size_t)row * 256 + col] = v;
      }
    }
  }
}

// ---------------- fused adj = emb@emb.T row top-7 ----------------
__global__ __launch_bounds__(256) void adj_topk(
    const float* __restrict__ emb, int* __restrict__ idx_o, int* __restrict__ keep_o) {
  __shared__ float rc[16][260];
  __shared__ float mv[16][112];
  __shared__ int mi[16][112];
  const int r0 = blockIdx.x * 16;
  const int tid = threadIdx.x;
  for (int e = tid; e < 16 * 256; e += 256) {
    int rr = e >> 8, cc = e & 255;
    rc[rr][cc] = emb[(size_t)(r0 + rr) * 256 + cc];
  }
  __syncthreads();
  const int tr = tid & 15, tc = tid >> 4;
  float bv[7];
  int bi[7];
#pragma unroll
  for (int k = 0; k < 7; ++k) { bv[k] = -1e38f; bi[k] = 0x7fffffff; }

  const float4* rp4 = (const float4*)(&rc[tr][0]);
  for (int c = tc; c < NN; c += 16) {
    const float4* ep = (const float4*)(emb + (size_t)c * 256);
    float4 s = make_float4(0.f, 0.f, 0.f, 0.f);
#pragma unroll 8
    for (int i = 0; i < 64; ++i) {
      float4 e4 = ep[i];
      float4 r4 = rp4[i];
      s.x = fmaf(r4.x, e4.x, s.x);
      s.y = fmaf(r4.y, e4.y, s.y);
      s.z = fmaf(r4.z, e4.z, s.z);
      s.w = fmaf(r4.w, e4.w, s.w);
    }
    float dot = (s.x + s.y) + (s.z + s.w);
    if (dot > bv[6] || (dot == bv[6] && c < bi[6])) {
      int p = 6;
      while (p > 0 && (dot > bv[p - 1] || (dot == bv[p - 1] && c < bi[p - 1]))) {
        bv[p] = bv[p - 1]; bi[p] = bi[p - 1]; --p;
      }
      bv[p] = dot; bi[p] = c;
    }
  }
#pragma unroll
  for (int k = 0; k < 7; ++k) { mv[tr][tc * 7 + k] = bv[k]; mi[tr][tc * 7 + k] = bi[k]; }
  __syncthreads();
  if (tid < 16) {
    int row = r0 + tid;
    int ptr[16];
#pragma unroll
    for (int l = 0; l < 16; ++l) ptr[l] = 0;
    for (int k = 0; k < 7; ++k) {
      float best = -1e38f; int bidx = 0x7fffffff; int bl = 0;
      for (int l = 0; l < 16; ++l) {
        float v = mv[tid][l * 7 + ptr[l]];
        int ii = mi[tid][l * 7 + ptr[l]];
        if (v > best || (v == best && ii < bidx)) { best = v; bidx = ii; bl = l; }
      }
      ptr[bl]++;
      idx_o[row * 7 + k] = bidx;
      keep_o[row * 7 + k] = (bidx > row && best != 0.0f) ? 1 : 0;
    }
  }
}

// ---------------- spatial kNN (exact integer distances) ----------------
__global__ __launch_bounds__(256) void spatial_topk(int* __restrict__ idx_o, int* __restrict__ keep_o) {
  int r = blockIdx.x * 256 + threadIdx.x;
  if (r >= NN) return;
  int ri = r / NHP, rj = r - (r / NHP) * NHP;
  int bd[7], bi[7];
#pragma unroll
  for (int k = 0; k < 7; ++k) { bd[k] = 0x7fffffff; bi[k] = 0x7fffffff; }
  int m = 0;
  for (int i2 = 0; i2 < NHP; ++i2) {
    int dy = ri - i2; int dy2 = dy * dy;
    for (int j2 = 0; j2 < NHP; ++j2, ++m) {
      int dx = rj - j2;
      int d = dy2 + dx * dx;
      if (d < bd[6]) {
        int p = 6;
        while (p > 0 && d < bd[p - 1]) { bd[p] = bd[p - 1]; bi[p] = bi[p - 1]; --p; }
        bd[p] = d; bi[p] = m;
      }
    }
  }
#pragma unroll
  for (int k = 0; k < 7; ++k) {
    idx_o[r * 7 + k] = bi[k];
    keep_o[r * 7 + k] = (bi[k] >= r && bd[k] != 0) ? 1 : 0;
  }
}

// ---------------- GATv2 aggregation, single head ----------------
__global__ __launch_bounds__(256) void gat_agg1(
    const float* __restrict__ xl, const float* __restrict__ xr,
    const void* __restrict__ att, long attoff, const void* __restrict__ gbias, long gboff,
    const int* __restrict__ nbr, const int* __restrict__ keep,
    float* __restrict__ out, const int* __restrict__ mode) {
  const int md = *mode;
  const int r = blockIdx.x;
  const int f = threadIdx.x;
  __shared__ int s_src[8];
  __shared__ int s_mask_s;
  __shared__ float red[4][8];
  if (f < 7) {
    int v = nbr[r * 7 + f];
    s_src[f] = ((unsigned)v < (unsigned)NN) ? v : 0;
  }
  if (f == 7) s_src[7] = r;
  if (f == 0) {
    int mk = 0x80;
    for (int e = 0; e < 7; ++e)
      if (keep[r * 7 + e] != 0) mk |= (1 << e);
    s_mask_s = mk;
  }
  __syncthreads();
  const int mask = s_mask_s;
  const int wid = f >> 6, lane = f & 63;

  float xrv = xr[(size_t)r * 256 + f];
  float attv = ldE(att, attoff + f, md);
  float xlv[8], part[8];
#pragma unroll
  for (int e = 0; e < 8; ++e) {
    xlv[e] = 0.f; part[e] = 0.f;
    if (mask & (1 << e)) {
      float v = xl[(size_t)s_src[e] * 256 + f];
      xlv[e] = v;
      float s = v + xrv;
      s = s > 0.f ? s : 0.2f * s;
      part[e] = s * attv;
    }
  }
#pragma unroll
  for (int e = 0; e < 8; ++e) {
    float v = part[e];
#pragma unroll
    for (int off = 32; off > 0; off >>= 1) v += __shfl_xor(v, off, 64);
    if (lane == 0) red[wid][e] = v;
  }
  __syncthreads();
  float m = -1e38f;
  float logit[8];
#pragma unroll
  for (int e = 0; e < 8; ++e) {
    logit[e] = red[0][e] + red[1][e] + red[2][e] + red[3][e];
    if (mask & (1 << e)) m = fmaxf(m, logit[e]);
  }
  float den = 0.f, al[8];
#pragma unroll
  for (int e = 0; e < 8; ++e) {
    al[e] = (mask & (1 << e)) ? expf(logit[e] - m) : 0.f;
    den += al[e];
  }
  float inv = 1.0f / den;
  float o = 0.f;
#pragma unroll
  for (int e = 0; e < 8; ++e) o = fmaf(al[e], xlv[e], o);
  o = o * inv + ldE(gbias, gboff + f, md);
  o = o > 0.f ? o : expm1f(o);
  out[(size_t)r * 256 + f] = o;
}

// ---------------- final: out = relu(cat(h2,h4) @ fc3_w + b) + h4 ----------------
__global__ __launch_bounds__(256) void fc3_final(
    const float* __restrict__ h2, const float* __restrict__ h4,
    const void* __restrict__ B, const void* __restrict__ bias,
    void* __restrict__ outp, const int* __restrict__ mode) {
  const int md = *mode;
  __shared__ float As[16][64];
  __shared__ float Bs[16][64];
  const int m0 = blockIdx.y * 64, n0 = blockIdx.x * 64;
  const int tid = threadIdx.x;
  const int tr = tid >> 4, tc = tid & 15;
  float acc[4][4];
#pragma unroll
  for (int i = 0; i < 4; ++i)
#pragma unroll
    for (int j = 0; j < 4; ++j) acc[i][j] = 0.f;

  for (int k0 = 0; k0 < 512; k0 += 16) {
    __syncthreads();
    {
      int r = tid >> 2, kq = tid & 3;
      int row = m0 + r;
      int k = k0 + kq * 4;
      float4 v = make_float4(0.f, 0.f, 0.f, 0.f);
      if (row < NN) {
        const float* src = (k < 256) ? (h2 + (size_t)row * 256 + k) : (h4 + (size_t)row * 256 + (k - 256));
        v = *(const float4*)src;
      }
      As[kq * 4 + 0][r] = v.x;
      As[kq * 4 + 1][r] = v.y;
      As[kq * 4 + 2][r] = v.z;
      As[kq * 4 + 3][r] = v.w;
    }
    {
      int kr = tid >> 4, nc = tid & 15;
      long bidx = (long)(k0 + kr) * 256 + n0 + nc * 4;
      if (md) {
        const unsigned short* bp = (const unsigned short*)B + bidx;
        Bs[kr][nc * 4 + 0] = bf2f(bp[0]);
        Bs[kr][nc * 4 + 1] = bf2f(bp[1]);
        Bs[kr][nc * 4 + 2] = bf2f(bp[2]);
        Bs[kr][nc * 4 + 3] = bf2f(bp[3]);
      } else {
        const float* bp = (const float*)B + bidx;
        Bs[kr][nc * 4 + 0] = bp[0];
        Bs[kr][nc * 4 + 1] = bp[1];
        Bs[kr][nc * 4 + 2] = bp[2];
        Bs[kr][nc * 4 + 3] = bp[3];
      }
    }
    __syncthreads();
#pragma unroll
    for (int kk = 0; kk < 16; ++kk) {
      float a[4], b[4];
#pragma unroll
      for (int i = 0; i < 4; ++i) a[i] = As[kk][tr * 4 + i];
#pragma unroll
      for (int j = 0; j < 4; ++j) b[j] = Bs[kk][tc * 4 + j];
#pragma unroll
      for (int i = 0; i < 4; ++i)
#pragma unroll
        for (int j = 0; j < 4; ++j) acc[i][j] = fmaf(a[i], b[j], acc[i][j]);
    }
  }
#pragma unroll
  for (int i = 0; i < 4; ++i) {
    int row = m0 + tr * 4 + i;
    if (row < NN) {
#pragma unroll
      for (int j = 0; j < 4; ++j) {
        int col = n0 + tc * 4 + j;
        float v = fmaxf(acc[i][j] + ldE(bias, col, md), 0.f) + h4[(size_t)row * 256 + col];
        if (md) ((__hip_bfloat16*)outp)[(size_t)row * 256 + col] = __float2bfloat16(v);
        else ((float*)outp)[(size_t)row * 256 + col] = v;
      }
    }
  }
}

// ---------------- launcher ----------------
extern "C" void kernel_launch(void* const* d_in, const int* in_sizes, int n_in,
                              void* d_out, int out_size, void* d_ws, size_t ws_size,
                              hipStream_t stream) {
  (void)in_sizes; (void)n_in; (void)out_size; (void)ws_size;
  const void* x    = d_in[0];
  const void* w1   = d_in[1];
  const void* b1   = d_in[2];
  const void* fc2w = d_in[3];
  const void* fc2b = d_in[4];
  const void* fc3w = d_in[5];
  const void* fc3b = d_in[6];
  const void* g_wl[4]   = {d_in[7],  d_in[13], d_in[19], d_in[25]};
  const void* g_bl[4]   = {d_in[8],  d_in[14], d_in[20], d_in[26]};
  const void* g_wr[4]   = {d_in[9],  d_in[15], d_in[21], d_in[27]};
  const void* g_br[4]   = {d_in[10], d_in[16], d_in[22], d_in[28]};
  const void* g_att[4]  = {d_in[11], d_in[17], d_in[23], d_in[29]};
  const void* g_bias[4] = {d_in[12], d_in[18], d_in[24], d_in[30]};

  float* ws = (float*)d_ws;
  int* mode = (int*)d_ws;
  size_t off = 64;  // 256B pad for the mode flag
  float* emb = ws + off; off += (size_t)NN * 256;
  float* xlh = ws + off; off += (size_t)NN * 256;
  float* xrh = ws + off; off += (size_t)NN * 256;
  float* hh  = ws + off; off += (size_t)NN * 256;
  float* xl2 = ws + off; off += (size_t)NN * 256;
  float* xr2 = ws + off; off += (size_t)NN * 256;
  float* h2  = ws + off; off += (size_t)NN * 256;
  float* h4  = ws + off; off += (size_t)NN * 256;
  int* idx1  = (int*)(ws + off); off += NN * 7;
  int* keep1 = (int*)(ws + off); off += NN * 7;
  int* idx2  = (int*)(ws + off); off += NN * 7;
  int* keep2 = (int*)(ws + off); off += NN * 7;
  // total ~29.9 MB

  dim3 blk(256);
  dim3 g4x57(4, 57);

  detect_mode<<<dim3(1), blk, 0, stream>>>((const unsigned short*)x, mode);

  // patch embed (temp in hh) then fc2 -> emb
  patch_gemm<<<g4x57, blk, 0, stream>>>(x, w1, b1, hh, mode);
  gemm_aw<1, 0><<<g4x57, blk, 0, stream>>>(hh, fc2w, 0, fc2b, 0, emb, NN, 256, 256, mode);

  // graphs
  adj_topk<<<dim3(225), blk, 0, stream>>>(emb, idx1, keep1);
  spatial_topk<<<dim3(15), blk, 0, stream>>>(idx2, keep2);

  // ---- feature graph: g1 (8 heads, head-at-a-time) accumulating g2's xl/xr ----
  for (int h = 0; h < 8; ++h) {
    gemm_aw<0, 0><<<g4x57, blk, 0, stream>>>(emb, g_wl[0], h * 256, g_bl[0], h * 256, xlh, NN, 256, 2048, mode);
    gemm_aw<0, 0><<<g4x57, blk, 0, stream>>>(emb, g_wr[0], h * 256, g_br[0], h * 256, xrh, NN, 256, 2048, mode);
    gat_agg1<<<dim3(NN), blk, 0, stream>>>(xlh, xrh, g_att[0], h * 256, g_bias[0], h * 256, idx1, keep1, hh, mode);
    if (h == 0) {
      gemm_aw<0, 0><<<g4x57, blk, 0, stream>>>(hh, g_wl[1], 0, g_bl[1], 0, xl2, NN, 256, 256, mode);
      gemm_aw<0, 0><<<g4x57, blk, 0, stream>>>(hh, g_wr[1], 0, g_br[1], 0, xr2, NN, 256, 256, mode);
    } else {
      gemm_aw<0, 1><<<g4x57, blk, 0, stream>>>(hh, g_wl[1], (long)h * 256 * 256, g_bl[1], 0, xl2, NN, 256, 256, mode);
      gemm_aw<0, 1><<<g4x57, blk, 0, stream>>>(hh, g_wr[1], (long)h * 256 * 256, g_br[1], 0, xr2, NN, 256, 256, mode);
    }
  }
  gat_agg1<<<dim3(NN), blk, 0, stream>>>(xl2, xr2, g_att[1], 0, g_bias[1], 0, idx1, keep1, h2, mode);

  // ---- spatial graph: g3 (8 heads) accumulating g4's xl/xr ----
  for (int h = 0; h < 8; ++h) {
    gemm_aw<0, 0><<<g4x57, blk, 0, stream>>>(emb, g_wl[2], h * 256, g_bl[2], h * 256, xlh, NN, 256, 2048, mode);
    gemm_aw<0, 0><<<g4x57, blk, 0, stream>>>(emb, g_wr[2], h * 256, g_br[2], h * 256, xrh, NN, 256, 2048, mode);
    gat_agg1<<<dim3(NN), blk, 0, stream>>>(xlh, xrh, g_att[2], h * 256, g_bias[2], h * 256, idx2, keep2, hh, mode);
    if (h == 0) {
      gemm_aw<0, 0><<<g4x57, blk, 0, stream>>>(hh, g_wl[3], 0, g_bl[3], 0, xl2, NN, 256, 256, mode);
      gemm_aw<0, 0><<<g4x57, blk, 0, stream>>>(hh, g_wr[3], 0, g_br[3], 0, xr2, NN, 256, 256, mode);
    } else {
      gemm_aw<0, 1><<<g4x57, blk, 0, stream>>>(hh, g_wl[3], (long)h * 256 * 256, g_bl[3], 0, xl2, NN, 256, 256, mode);
      gemm_aw<0, 1><<<g4x57, blk, 0, stream>>>(hh, g_wr[3], (long)h * 256 * 256, g_br[3], 0, xr2, NN, 256, 256, mode);
    }
  }
  gat_agg1<<<dim3(NN), blk, 0, stream>>>(xl2, xr2, g_att[3], 0, g_bias[3], 0, idx2, keep2, h4, mode);

  // head: relu(cat(h2,h4)@fc3 + b) + h4
  fc3_final<<<g4x57, blk, 0, stream>>>(h2, h4, fc3w, fc3b, d_out, mode);
}

// Round 4
// 2996.966 us; speedup vs baseline: 1.7562x; 1.7562x over previous
//
#include <hip/hip_runtime.h>
#include <hip/hip_bf16.h>
#include <math.h>

// ---------------- constants ----------------
#define NN 3600      // nodes
#define HIMG 300
#define WIMG 300
#define NHP 60       // patches per side

__device__ __forceinline__ float bf2f(unsigned short u) {
  union { unsigned int i; float f; } v; v.i = ((unsigned int)u) << 16; return v.f;
}
// mode: 1 = buffers are bf16, 0 = buffers are f32
__device__ __forceinline__ float ldE(const void* p, long i, int md) {
  return md ? bf2f(((const unsigned short*)p)[i]) : ((const float*)p)[i];
}

// ---------------- dtype detector ----------------
__global__ void detect_mode(const unsigned short* __restrict__ x, int* __restrict__ flag) {
  if (threadIdx.x == 0 && blockIdx.x == 0) {
    int bad = 0;
    for (int i = 0; i < 8192; ++i) {
      int e = (x[i] >> 7) & 0xFF;
      if (e >= 0x90) bad = 1;
    }
    flag[0] = bad ? 0 : 1;
  }
}

// ---------------- patch-embed GEMM: emb1 = relu(patches @ W1^T + b1) ----------------
__global__ __launch_bounds__(256) void patch_gemm(
    const void* __restrict__ x, const void* __restrict__ w,
    const void* __restrict__ bias, float* __restrict__ out, const int* __restrict__ mode) {
  const int md = *mode;
  __shared__ float As[25][64];
  __shared__ float Bs[25][64];
  const int m0 = blockIdx.y * 64, n0 = blockIdx.x * 64;
  const int tid = threadIdx.x;
  const int tr = tid >> 4, tc = tid & 15;
  float acc[4][4];
#pragma unroll
  for (int i = 0; i < 4; ++i)
#pragma unroll
    for (int j = 0; j < 4; ++j) acc[i][j] = 0.f;

  for (int c = 0; c < 256; ++c) {
    __syncthreads();
    for (int e = tid; e < 1600; e += 256) {
      int p = e / 25, q = e - p * 25;
      int ki = q / 5, li = q - ki * 5;
      int n = m0 + p;
      float v = 0.f;
      if (n < NN) {
        int ni = n / NHP, nj = n - ni * NHP;
        v = ldE(x, (long)c * (HIMG * WIMG) + (5 * ni + ki) * WIMG + 5 * nj + li, md);
      }
      As[q][p] = v;
    }
    for (int e = tid; e < 1600; e += 256) {
      int o = e / 25, q = e - o * 25;
      Bs[q][o] = ldE(w, (long)(n0 + o) * 6400 + c * 25 + q, md);
    }
    __syncthreads();
#pragma unroll
    for (int kk = 0; kk < 25; ++kk) {
      float a[4], b[4];
#pragma unroll
      for (int i = 0; i < 4; ++i) a[i] = As[kk][tr * 4 + i];
#pragma unroll
      for (int j = 0; j < 4; ++j) b[j] = Bs[kk][tc * 4 + j];
#pragma unroll
      for (int i = 0; i < 4; ++i)
#pragma unroll
        for (int j = 0; j < 4; ++j) acc[i][j] = fmaf(a[i], b[j], acc[i][j]);
    }
  }
#pragma unroll
  for (int i = 0; i < 4; ++i) {
    int row = m0 + tr * 4 + i;
    if (row < NN) {
#pragma unroll
      for (int j = 0; j < 4; ++j) {
        int col = n0 + tc * 4 + j;
        float v = acc[i][j] + ldE(bias, col, md);
        out[(size_t)row * 256 + col] = fmaxf(v, 0.f);
      }
    }
  }
}

// ---------------- paired GEMM: z=0 -> (B0,bias0,C0), z=1 -> (B1,bias1,C1) ----------------
// C[row*cld + col] = act(A[M,K] @ B[boff..](ldb) + bias[biasoff+col])   (ACC=0)
//                  = C + A@B                                            (ACC=1)
template <int ACT, int ACC>
__global__ __launch_bounds__(256) void gemm_lr(
    const float* __restrict__ A, const void* __restrict__ B0, const void* __restrict__ B1,
    long boff, const void* __restrict__ bias0, const void* __restrict__ bias1, long biasoff,
    float* __restrict__ C0, float* __restrict__ C1, int cld,
    int M, int K, int ldb, const int* __restrict__ mode) {
  const int md = *mode;
  const void* B = blockIdx.z ? B1 : B0;
  const void* bias = blockIdx.z ? bias1 : bias0;
  float* C = blockIdx.z ? C1 : C0;
  __shared__ float As[16][64];
  __shared__ float Bs[16][64];
  const int m0 = blockIdx.y * 64, n0 = blockIdx.x * 64;
  const int tid = threadIdx.x;
  const int tr = tid >> 4, tc = tid & 15;
  float acc[4][4];
#pragma unroll
  for (int i = 0; i < 4; ++i)
#pragma unroll
    for (int j = 0; j < 4; ++j) acc[i][j] = 0.f;

  for (int k0 = 0; k0 < K; k0 += 16) {
    __syncthreads();
    {
      int r = tid >> 2, kq = tid & 3;
      int row = m0 + r;
      float4 v = make_float4(0.f, 0.f, 0.f, 0.f);
      if (row < M) v = *(const float4*)(A + (size_t)row * K + k0 + kq * 4);
      As[kq * 4 + 0][r] = v.x;
      As[kq * 4 + 1][r] = v.y;
      As[kq * 4 + 2][r] = v.z;
      As[kq * 4 + 3][r] = v.w;
    }
    {
      int kr = tid >> 4, nc = tid & 15;
      long bidx = (long)(k0 + kr) * ldb + boff + n0 + nc * 4;
      if (md) {
        const unsigned short* bp = (const unsigned short*)B + bidx;
        Bs[kr][nc * 4 + 0] = bf2f(bp[0]);
        Bs[kr][nc * 4 + 1] = bf2f(bp[1]);
        Bs[kr][nc * 4 + 2] = bf2f(bp[2]);
        Bs[kr][nc * 4 + 3] = bf2f(bp[3]);
      } else {
        float4 v = *(const float4*)((const float*)B + bidx);
        Bs[kr][nc * 4 + 0] = v.x;
        Bs[kr][nc * 4 + 1] = v.y;
        Bs[kr][nc * 4 + 2] = v.z;
        Bs[kr][nc * 4 + 3] = v.w;
      }
    }
    __syncthreads();
#pragma unroll
    for (int kk = 0; kk < 16; ++kk) {
      float a[4], b[4];
#pragma unroll
      for (int i = 0; i < 4; ++i) a[i] = As[kk][tr * 4 + i];
#pragma unroll
      for (int j = 0; j < 4; ++j) b[j] = Bs[kk][tc * 4 + j];
#pragma unroll
      for (int i = 0; i < 4; ++i)
#pragma unroll
        for (int j = 0; j < 4; ++j) acc[i][j] = fmaf(a[i], b[j], acc[i][j]);
    }
  }
#pragma unroll
  for (int i = 0; i < 4; ++i) {
    int row = m0 + tr * 4 + i;
    if (row < M) {
#pragma unroll
      for (int j = 0; j < 4; ++j) {
        int col = n0 + tc * 4 + j;
        float v;
        if (ACC == 1) {
          v = C[(size_t)row * cld + col] + acc[i][j];
        } else {
          v = acc[i][j] + ldE(bias, biasoff + col, md);
          if (ACT == 1) v = fmaxf(v, 0.f);
        }
        C[(size_t)row * cld + col] = v;
      }
    }
  }
}

// ---------------- fused adj = emb@emb.T row top-7 ----------------
__global__ __launch_bounds__(256) void adj_topk(
    const float* __restrict__ emb, int* __restrict__ idx_o, int* __restrict__ keep_o) {
  __shared__ float rc[16][260];
  __shared__ float mv[16][112];
  __shared__ int mi[16][112];
  const int r0 = blockIdx.x * 16;
  const int tid = threadIdx.x;
  for (int e = tid; e < 16 * 256; e += 256) {
    int rr = e >> 8, cc = e & 255;
    rc[rr][cc] = emb[(size_t)(r0 + rr) * 256 + cc];
  }
  __syncthreads();
  const int tr = tid & 15, tc = tid >> 4;
  float bv[7];
  int bi[7];
#pragma unroll
  for (int k = 0; k < 7; ++k) { bv[k] = -1e38f; bi[k] = 0x7fffffff; }

  const float4* rp4 = (const float4*)(&rc[tr][0]);
  for (int c = tc; c < NN; c += 16) {
    const float4* ep = (const float4*)(emb + (size_t)c * 256);
    float4 s = make_float4(0.f, 0.f, 0.f, 0.f);
#pragma unroll 8
    for (int i = 0; i < 64; ++i) {
      float4 e4 = ep[i];
      float4 r4 = rp4[i];
      s.x = fmaf(r4.x, e4.x, s.x);
      s.y = fmaf(r4.y, e4.y, s.y);
      s.z = fmaf(r4.z, e4.z, s.z);
      s.w = fmaf(r4.w, e4.w, s.w);
    }
    float dot = (s.x + s.y) + (s.z + s.w);
    if (dot > bv[6] || (dot == bv[6] && c < bi[6])) {
      int p = 6;
      while (p > 0 && (dot > bv[p - 1] || (dot == bv[p - 1] && c < bi[p - 1]))) {
        bv[p] = bv[p - 1]; bi[p] = bi[p - 1]; --p;
      }
      bv[p] = dot; bi[p] = c;
    }
  }
#pragma unroll
  for (int k = 0; k < 7; ++k) { mv[tr][tc * 7 + k] = bv[k]; mi[tr][tc * 7 + k] = bi[k]; }
  __syncthreads();
  if (tid < 16) {
    int row = r0 + tid;
    int ptr[16];
#pragma unroll
    for (int l = 0; l < 16; ++l) ptr[l] = 0;
    for (int k = 0; k < 7; ++k) {
      float best = -1e38f; int bidx = 0x7fffffff; int bl = 0;
      for (int l = 0; l < 16; ++l) {
        float v = mv[tid][l * 7 + ptr[l]];
        int ii = mi[tid][l * 7 + ptr[l]];
        if (v > best || (v == best && ii < bidx)) { best = v; bidx = ii; bl = l; }
      }
      ptr[bl]++;
      idx_o[row * 7 + k] = bidx;
      keep_o[row * 7 + k] = (bidx > row && best != 0.0f) ? 1 : 0;
    }
  }
}

// ---------------- spatial kNN via 5x5 window (provably identical to full scan) ----------------
// 7th-nearest d^2 <= 5 at every position; any cell outside |di|,|dj|<=2 has d^2 >= 9.
// Window iterated in ascending linear index -> identical (d asc, idx asc) order.
__global__ __launch_bounds__(256) void spatial_topk(int* __restrict__ idx_o, int* __restrict__ keep_o) {
  int r = blockIdx.x * 256 + threadIdx.x;
  if (r >= NN) return;
  int ri = r / NHP, rj = r - (r / NHP) * NHP;
  int bd[7], bi[7];
#pragma unroll
  for (int k = 0; k < 7; ++k) { bd[k] = 0x7fffffff; bi[k] = 0x7fffffff; }
  int ilo = ri - 2 > 0 ? ri - 2 : 0, ihi = ri + 2 < NHP - 1 ? ri + 2 : NHP - 1;
  int jlo = rj - 2 > 0 ? rj - 2 : 0, jhi = rj + 2 < NHP - 1 ? rj + 2 : NHP - 1;
  for (int i2 = ilo; i2 <= ihi; ++i2) {
    int dy = ri - i2; int dy2 = dy * dy;
    for (int j2 = jlo; j2 <= jhi; ++j2) {
      int dx = rj - j2;
      int d = dy2 + dx * dx;
      int m = i2 * NHP + j2;
      if (d < bd[6]) {
        int p = 6;
        while (p > 0 && d < bd[p - 1]) { bd[p] = bd[p - 1]; bi[p] = bi[p - 1]; --p; }
        bd[p] = d; bi[p] = m;
      }
    }
  }
#pragma unroll
  for (int k = 0; k < 7; ++k) {
    idx_o[r * 7 + k] = bi[k];
    keep_o[r * 7 + k] = (bi[k] >= r && bd[k] != 0) ? 1 : 0;
  }
}

// ---------------- GATv2 aggregation, single head (cld-strided in/out = 256) ----------------
__global__ __launch_bounds__(256) void gat_agg1(
    const float* __restrict__ xl, const float* __restrict__ xr,
    const void* __restrict__ att, long attoff, const void* __restrict__ gbias, long gboff,
    const int* __restrict__ nbr, const int* __restrict__ keep,
    float* __restrict__ out, const int* __restrict__ mode) {
  const int md = *mode;
  const int r = blockIdx.x;
  const int f = threadIdx.x;
  __shared__ int s_src[8];
  __shared__ int s_mask_s;
  __shared__ float red[4][8];
  if (f < 7) {
    int v = nbr[r * 7 + f];
    s_src[f] = ((unsigned)v < (unsigned)NN) ? v : 0;
  }
  if (f == 7) s_src[7] = r;
  if (f == 0) {
    int mk = 0x80;
    for (int e = 0; e < 7; ++e)
      if (keep[r * 7 + e] != 0) mk |= (1 << e);
    s_mask_s = mk;
  }
  __syncthreads();
  const int mask = s_mask_s;
  const int wid = f >> 6, lane = f & 63;

  float xrv = xr[(size_t)r * 256 + f];
  float attv = ldE(att, attoff + f, md);
  float xlv[8], part[8];
#pragma unroll
  for (int e = 0; e < 8; ++e) {
    xlv[e] = 0.f; part[e] = 0.f;
    if (mask & (1 << e)) {
      float v = xl[(size_t)s_src[e] * 256 + f];
      xlv[e] = v;
      float s = v + xrv;
      s = s > 0.f ? s : 0.2f * s;
      part[e] = s * attv;
    }
  }
#pragma unroll
  for (int e = 0; e < 8; ++e) {
    float v = part[e];
#pragma unroll
    for (int off = 32; off > 0; off >>= 1) v += __shfl_xor(v, off, 64);
    if (lane == 0) red[wid][e] = v;
  }
  __syncthreads();
  float m = -1e38f;
  float logit[8];
#pragma unroll
  for (int e = 0; e < 8; ++e) {
    logit[e] = red[0][e] + red[1][e] + red[2][e] + red[3][e];
    if (mask & (1 << e)) m = fmaxf(m, logit[e]);
  }
  float den = 0.f, al[8];
#pragma unroll
  for (int e = 0; e < 8; ++e) {
    al[e] = (mask & (1 << e)) ? expf(logit[e] - m) : 0.f;
    den += al[e];
  }
  float inv = 1.0f / den;
  float o = 0.f;
#pragma unroll
  for (int e = 0; e < 8; ++e) o = fmaf(al[e], xlv[e], o);
  o = o * inv + ldE(gbias, gboff + f, md);
  o = o > 0.f ? o : expm1f(o);
  out[(size_t)r * 256 + f] = o;
}

// ---------------- GATv2 aggregation, 8 heads, 2048-strided buffers (wide path) ----------------
__global__ __launch_bounds__(256) void gat_agg8(
    const float* __restrict__ xl, const float* __restrict__ xr,
    const void* __restrict__ att, const void* __restrict__ gbias,
    const int* __restrict__ nbr, const int* __restrict__ keep,
    float* __restrict__ out, const int* __restrict__ mode) {
  const int md = *mode;
  const int r = blockIdx.x;
  const int f = threadIdx.x;
  __shared__ int s_src[8];
  __shared__ int s_mask_s;
  __shared__ float red[4][8];
  if (f < 7) {
    int v = nbr[r * 7 + f];
    s_src[f] = ((unsigned)v < (unsigned)NN) ? v : 0;
  }
  if (f == 7) s_src[7] = r;
  if (f == 0) {
    int mk = 0x80;
    for (int e = 0; e < 7; ++e)
      if (keep[r * 7 + e] != 0) mk |= (1 << e);
    s_mask_s = mk;
  }
  __syncthreads();
  const int mask = s_mask_s;
  const int wid = f >> 6, lane = f & 63;

  for (int h = 0; h < 8; ++h) {
    float xrv = xr[(size_t)r * 2048 + h * 256 + f];
    float attv = ldE(att, h * 256 + f, md);
    float xlv[8], part[8];
#pragma unroll
    for (int e = 0; e < 8; ++e) {
      xlv[e] = 0.f; part[e] = 0.f;
      if (mask & (1 << e)) {
        float v = xl[(size_t)s_src[e] * 2048 + h * 256 + f];
        xlv[e] = v;
        float s = v + xrv;
        s = s > 0.f ? s : 0.2f * s;
        part[e] = s * attv;
      }
    }
#pragma unroll
    for (int e = 0; e < 8; ++e) {
      float v = part[e];
#pragma unroll
      for (int off = 32; off > 0; off >>= 1) v += __shfl_xor(v, off, 64);
      if (lane == 0) red[wid][e] = v;
    }
    __syncthreads();
    float m = -1e38f;
    float logit[8];
#pragma unroll
    for (int e = 0; e < 8; ++e) {
      logit[e] = red[0][e] + red[1][e] + red[2][e] + red[3][e];
      if (mask & (1 << e)) m = fmaxf(m, logit[e]);
    }
    float den = 0.f, al[8];
#pragma unroll
    for (int e = 0; e < 8; ++e) {
      al[e] = (mask & (1 << e)) ? expf(logit[e] - m) : 0.f;
      den += al[e];
    }
    float inv = 1.0f / den;
    float o = 0.f;
#pragma unroll
    for (int e = 0; e < 8; ++e) o = fmaf(al[e], xlv[e], o);
    o = o * inv + ldE(gbias, h * 256 + f, md);
    o = o > 0.f ? o : expm1f(o);
    out[(size_t)r * 2048 + h * 256 + f] = o;
    __syncthreads();
  }
}

// ---------------- final: out = relu(cat(h2,h4) @ fc3_w + b) + h4 ----------------
__global__ __launch_bounds__(256) void fc3_final(
    const float* __restrict__ h2, const float* __restrict__ h4,
    const void* __restrict__ B, const void* __restrict__ bias,
    void* __restrict__ outp, const int* __restrict__ mode) {
  const int md = *mode;
  __shared__ float As[16][64];
  __shared__ float Bs[16][64];
  const int m0 = blockIdx.y * 64, n0 = blockIdx.x * 64;
  const int tid = threadIdx.x;
  const int tr = tid >> 4, tc = tid & 15;
  float acc[4][4];
#pragma unroll
  for (int i = 0; i < 4; ++i)
#pragma unroll
    for (int j = 0; j < 4; ++j) acc[i][j] = 0.f;

  for (int k0 = 0; k0 < 512; k0 += 16) {
    __syncthreads();
    {
      int r = tid >> 2, kq = tid & 3;
      int row = m0 + r;
      int k = k0 + kq * 4;
      float4 v = make_float4(0.f, 0.f, 0.f, 0.f);
      if (row < NN) {
        const float* src = (k < 256) ? (h2 + (size_t)row * 256 + k) : (h4 + (size_t)row * 256 + (k - 256));
        v = *(const float4*)src;
      }
      As[kq * 4 + 0][r] = v.x;
      As[kq * 4 + 1][r] = v.y;
      As[kq * 4 + 2][r] = v.z;
      As[kq * 4 + 3][r] = v.w;
    }
    {
      int kr = tid >> 4, nc = tid & 15;
      long bidx = (long)(k0 + kr) * 256 + n0 + nc * 4;
      if (md) {
        const unsigned short* bp = (const unsigned short*)B + bidx;
        Bs[kr][nc * 4 + 0] = bf2f(bp[0]);
        Bs[kr][nc * 4 + 1] = bf2f(bp[1]);
        Bs[kr][nc * 4 + 2] = bf2f(bp[2]);
        Bs[kr][nc * 4 + 3] = bf2f(bp[3]);
      } else {
        float4 v = *(const float4*)((const float*)B + bidx);
        Bs[kr][nc * 4 + 0] = v.x;
        Bs[kr][nc * 4 + 1] = v.y;
        Bs[kr][nc * 4 + 2] = v.z;
        Bs[kr][nc * 4 + 3] = v.w;
      }
    }
    __syncthreads();
#pragma unroll
    for (int kk = 0; kk < 16; ++kk) {
      float a[4], b[4];
#pragma unroll
      for (int i = 0; i < 4; ++i) a[i] = As[kk][tr * 4 + i];
#pragma unroll
      for (int j = 0; j < 4; ++j) b[j] = Bs[kk][tc * 4 + j];
#pragma unroll
      for (int i = 0; i < 4; ++i)
#pragma unroll
        for (int j = 0; j < 4; ++j) acc[i][j] = fmaf(a[i], b[j], acc[i][j]);
    }
  }
#pragma unroll
  for (int i = 0; i < 4; ++i) {
    int row = m0 + tr * 4 + i;
    if (row < NN) {
#pragma unroll
      for (int j = 0; j < 4; ++j) {
        int col = n0 + tc * 4 + j;
        float v = fmaxf(acc[i][j] + ldE(bias, col, md), 0.f) + h4[(size_t)row * 256 + col];
        if (md) ((__hip_bfloat16*)outp)[(size_t)row * 256 + col] = __float2bfloat16(v);
        else ((float*)outp)[(size_t)row * 256 + col] = v;
      }
    }
  }
}

// ---------------- launcher ----------------
extern "C" void kernel_launch(void* const* d_in, const int* in_sizes, int n_in,
                              void* d_out, int out_size, void* d_ws, size_t ws_size,
                              hipStream_t stream) {
  (void)in_sizes; (void)n_in; (void)out_size;
  const void* x    = d_in[0];
  const void* w1   = d_in[1];
  const void* b1   = d_in[2];
  const void* fc2w = d_in[3];
  const void* fc2b = d_in[4];
  const void* fc3w = d_in[5];
  const void* fc3b = d_in[6];
  const void* g_wl[4]   = {d_in[7],  d_in[13], d_in[19], d_in[25]};
  const void* g_bl[4]   = {d_in[8],  d_in[14], d_in[20], d_in[26]};
  const void* g_wr[4]   = {d_in[9],  d_in[15], d_in[21], d_in[27]};
  const void* g_br[4]   = {d_in[10], d_in[16], d_in[22], d_in[28]};
  const void* g_att[4]  = {d_in[11], d_in[17], d_in[23], d_in[29]};
  const void* g_bias[4] = {d_in[12], d_in[18], d_in[24], d_in[30]};

  float* ws = (float*)d_ws;
  int* mode = (int*)d_ws;
  size_t off = 64;  // 256B pad for the mode flag
  float* emb = ws + off; off += (size_t)NN * 256;
  float* xl2 = ws + off; off += (size_t)NN * 256;
  float* xr2 = ws + off; off += (size_t)NN * 256;
  float* h2  = ws + off; off += (size_t)NN * 256;
  float* h4  = ws + off; off += (size_t)NN * 256;
  int* idx1  = (int*)(ws + off); off += NN * 7;
  int* keep1 = (int*)(ws + off); off += NN * 7;
  int* idx2  = (int*)(ws + off); off += NN * 7;
  int* keep2 = (int*)(ws + off); off += NN * 7;
  const size_t base_off = off;
  const size_t wide_floats = base_off + 3 * (size_t)NN * 2048;
  const bool wide = ws_size >= wide_floats * sizeof(float);

  dim3 blk(256);
  dim3 g4x57(4, 57);
  const int* idxs[2]  = {idx1, idx2};
  const int* keeps[2] = {keep1, keep2};
  float* houts[2] = {h2, h4};

  detect_mode<<<dim3(1), blk, 0, stream>>>((const unsigned short*)x, mode);

  if (wide) {
    float* xl_w = ws + base_off;
    float* xr_w = xl_w + (size_t)NN * 2048;
    float* hh_w = xr_w + (size_t)NN * 2048;

    // patch embed (temp in xl_w) then fc2 -> emb
    patch_gemm<<<g4x57, blk, 0, stream>>>(x, w1, b1, xl_w, mode);
    gemm_lr<1, 0><<<dim3(4, 57, 1), blk, 0, stream>>>(xl_w, fc2w, fc2w, 0, fc2b, fc2b, 0,
                                                      emb, emb, 256, NN, 256, 256, mode);
    adj_topk<<<dim3(225), blk, 0, stream>>>(emb, idx1, keep1);
    spatial_topk<<<dim3(15), blk, 0, stream>>>(idx2, keep2);

    for (int g = 0; g < 2; ++g) {
      int a = g * 2, b = g * 2 + 1;
      gemm_lr<0, 0><<<dim3(32, 57, 2), blk, 0, stream>>>(emb, g_wl[a], g_wr[a], 0,
                                                         g_bl[a], g_br[a], 0,
                                                         xl_w, xr_w, 2048, NN, 256, 2048, mode);
      gat_agg8<<<dim3(NN), blk, 0, stream>>>(xl_w, xr_w, g_att[a], g_bias[a], idxs[g], keeps[g], hh_w, mode);
      gemm_lr<0, 0><<<dim3(4, 57, 2), blk, 0, stream>>>(hh_w, g_wl[b], g_wr[b], 0,
                                                        g_bl[b], g_br[b], 0,
                                                        xl2, xr2, 256, NN, 2048, 256, mode);
      gat_agg1<<<dim3(NN), blk, 0, stream>>>(xl2, xr2, g_att[b], 0, g_bias[b], 0,
                                             idxs[g], keeps[g], houts[g], mode);
    }
  } else {
    float* xlh = ws + base_off;
    float* xrh = xlh + (size_t)NN * 256;
    float* hh  = xrh + (size_t)NN * 256;

    patch_gemm<<<g4x57, blk, 0, stream>>>(x, w1, b1, hh, mode);
    gemm_lr<1, 0><<<dim3(4, 57, 1), blk, 0, stream>>>(hh, fc2w, fc2w, 0, fc2b, fc2b, 0,
                                                      emb, emb, 256, NN, 256, 256, mode);
    adj_topk<<<dim3(225), blk, 0, stream>>>(emb, idx1, keep1);
    spatial_topk<<<dim3(15), blk, 0, stream>>>(idx2, keep2);

    for (int g = 0; g < 2; ++g) {
      int a = g * 2, b = g * 2 + 1;
      for (int h = 0; h < 8; ++h) {
        gemm_lr<0, 0><<<dim3(4, 57, 2), blk, 0, stream>>>(emb, g_wl[a], g_wr[a], h * 256,
                                                          g_bl[a], g_br[a], h * 256,
                                                          xlh, xrh, 256, NN, 256, 2048, mode);
        gat_agg1<<<dim3(NN), blk, 0, stream>>>(xlh, xrh, g_att[a], h * 256, g_bias[a], h * 256,
                                               idxs[g], keeps[g], hh, mode);
        if (h == 0) {
          gemm_lr<0, 0><<<dim3(4, 57, 2), blk, 0, stream>>>(hh, g_wl[b], g_wr[b], 0,
                                                            g_bl[b], g_br[b], 0,
                                                            xl2, xr2, 256, NN, 256, 256, mode);
        } else {
          gemm_lr<0, 1><<<dim3(4, 57, 2), blk, 0, stream>>>(hh, g_wl[b], g_wr[b], (long)h * 256 * 256,
                                                            g_bl[b], g_br[b], 0,
                                                            xl2, xr2, 256, NN, 256, 256, mode);
        }
      }
      gat_agg1<<<dim3(NN), blk, 0, stream>>>(xl2, xr2, g_att[b], 0, g_bias[b], 0,
                                             idxs[g], keeps[g], houts[g], mode);
    }
  }

  fc3_final<<<g4x57, blk, 0, stream>>>(h2, h4, fc3w, fc3b, d_out, mode);
}

// Round 5
// 1685.474 us; speedup vs baseline: 3.1226x; 1.7781x over previous
//
#include <hip/hip_runtime.h>
#include <hip/hip_bf16.h>
#include <math.h>

#define NN 3600
#define HIMG 300
#define WIMG 300
#define NHP 60

__device__ __forceinline__ float bf2f(unsigned short u) {
  union { unsigned int i; float f; } v; v.i = ((unsigned int)u) << 16; return v.f;
}
// mode: 1 = buffers are bf16, 0 = buffers are f32
__device__ __forceinline__ float ldE(const void* p, long i, int md) {
  return md ? bf2f(((const unsigned short*)p)[i]) : ((const float*)p)[i];
}

__global__ void detect_mode(const unsigned short* __restrict__ x, int* __restrict__ flag) {
  if (threadIdx.x == 0 && blockIdx.x == 0) {
    int bad = 0;
    for (int i = 0; i < 8192; ++i) {
      int e = (x[i] >> 7) & 0xFF;
      if (e >= 0x90) bad = 1;
    }
    flag[0] = bad ? 0 : 1;
  }
}

// ================= unified 64x64 GEMM, conflict-free LDS, K-split =================
// STORE: 0 = C = act(acc + bias), 1 = C += acc, 2 = part[z] = acc (raw partial)
// z = pair*KS + ks; k-range = [ks*kchunk, ks*kchunk+kchunk)
template <int STORE, int ACT>
__global__ __launch_bounds__(256) void gemm_u(
    const float* __restrict__ A, const void* __restrict__ B0, const void* __restrict__ B1,
    long boff, const void* __restrict__ bias0, const void* __restrict__ bias1, long biasoff,
    float* __restrict__ C0, float* __restrict__ C1, float* __restrict__ part, int cld,
    int M, int lda, int kchunk, int KS, int ldb, const int* __restrict__ mode) {
  const int md = *mode;
  const int z = blockIdx.z;
  const int pair = z / KS, ks = z - pair * KS;
  const void* B = pair ? B1 : B0;
  const void* bias = pair ? bias1 : bias0;
  float* C = pair ? C1 : C0;
  __shared__ float As[16][68];   // [k][m], pad 68: b128 reads conflict-free
  __shared__ float Bs[16][68];   // [k][n]
  const int m0 = blockIdx.y * 64, n0 = blockIdx.x * 64;
  const int tid = threadIdx.x;
  const int tr = tid >> 4, tc = tid & 15;
  const int ar = tid >> 2, akq = tid & 3;
  const int bkr = tid >> 4, bnc = tid & 15;
  const int arow = m0 + ar;
  float acc[4][4] = {};

  const int kb = ks * kchunk, ke = kb + kchunk;
  for (int k0 = kb; k0 < ke; k0 += 16) {
    __syncthreads();
    {
      float4 v = make_float4(0.f, 0.f, 0.f, 0.f);
      if (arow < M) v = *(const float4*)(A + (size_t)arow * lda + k0 + akq * 4);
      As[akq * 4 + 0][ar] = v.x;
      As[akq * 4 + 1][ar] = v.y;
      As[akq * 4 + 2][ar] = v.z;
      As[akq * 4 + 3][ar] = v.w;
    }
    {
      long bidx = (long)(k0 + bkr) * ldb + boff + n0 + bnc * 4;
      if (md) {
        ushort4 u = *(const ushort4*)((const unsigned short*)B + bidx);
        Bs[bkr][bnc * 4 + 0] = bf2f(u.x);
        Bs[bkr][bnc * 4 + 1] = bf2f(u.y);
        Bs[bkr][bnc * 4 + 2] = bf2f(u.z);
        Bs[bkr][bnc * 4 + 3] = bf2f(u.w);
      } else {
        float4 v = *(const float4*)((const float*)B + bidx);
        Bs[bkr][bnc * 4 + 0] = v.x;
        Bs[bkr][bnc * 4 + 1] = v.y;
        Bs[bkr][bnc * 4 + 2] = v.z;
        Bs[bkr][bnc * 4 + 3] = v.w;
      }
    }
    __syncthreads();
#pragma unroll
    for (int kk = 0; kk < 16; ++kk) {
      float4 av = *(const float4*)&As[kk][tr * 4];
      float4 bv = *(const float4*)&Bs[kk][tc * 4];
      float a[4] = {av.x, av.y, av.z, av.w};
      float b[4] = {bv.x, bv.y, bv.z, bv.w};
#pragma unroll
      for (int i = 0; i < 4; ++i)
#pragma unroll
        for (int j = 0; j < 4; ++j) acc[i][j] = fmaf(a[i], b[j], acc[i][j]);
    }
  }
#pragma unroll
  for (int i = 0; i < 4; ++i) {
    int row = m0 + tr * 4 + i;
    if (row < M) {
#pragma unroll
      for (int j = 0; j < 4; ++j) {
        int col = n0 + tc * 4 + j;
        if (STORE == 2) {
          part[((size_t)z * M + row) * cld + col] = acc[i][j];
        } else if (STORE == 1) {
          C[(size_t)row * cld + col] += acc[i][j];
        } else {
          float v = acc[i][j] + ldE(bias, biasoff + col, md);
          if (ACT == 1) v = fmaxf(v, 0.f);
          C[(size_t)row * cld + col] = v;
        }
      }
    }
  }
}

// reduce partials: C_pair = act(sum_ks part[pair*KS+ks] + bias_pair)
template <int ACT>
__global__ __launch_bounds__(256) void reduce_u(
    const float* __restrict__ part, int KS, int M, int ncols,
    const void* __restrict__ bias0, const void* __restrict__ bias1, long biasoff,
    float* __restrict__ C0, float* __restrict__ C1, int cld, const int* __restrict__ mode) {
  const int md = *mode;
  const int pair = blockIdx.z;
  const void* bias = pair ? bias1 : bias0;
  float* C = pair ? C1 : C0;
  size_t total = (size_t)M * ncols;
  for (size_t i = (size_t)blockIdx.x * blockDim.x + threadIdx.x; i < total;
       i += (size_t)gridDim.x * blockDim.x) {
    int row = (int)(i / ncols), col = (int)(i - (size_t)row * ncols);
    float s = 0.f;
    for (int ks = 0; ks < KS; ++ks)
      s += part[(((size_t)(pair * KS + ks)) * M + row) * ncols + col];
    s += ldE(bias, biasoff + col, md);
    if (ACT == 1) s = fmaxf(s, 0.f);
    C[(size_t)row * cld + col] = s;
  }
}

// ============ patch-embed partial GEMM (channel-split), conflict-free LDS ============
__global__ __launch_bounds__(256) void patch_part(
    const void* __restrict__ x, const void* __restrict__ w,
    float* __restrict__ part, int CPB, const int* __restrict__ mode) {
  const int md = *mode;
  __shared__ float As[25][68];   // [q][patch]
  __shared__ float Bs[25][68];   // [q][out]
  const int m0 = blockIdx.y * 64, n0 = blockIdx.x * 64;
  const int tid = threadIdx.x;
  const int tr = tid >> 4, tc = tid & 15;
  const int z = blockIdx.z;
  float acc[4][4] = {};
  const int c0 = z * CPB;
  for (int c = c0; c < c0 + CPB; ++c) {
    __syncthreads();
    for (int e = tid; e < 1600; e += 256) {
      int p = e / 25, q = e - p * 25;
      int ki = q / 5, li = q - ki * 5;
      int n = m0 + p;
      float v = 0.f;
      if (n < NN) {
        int ni = n / NHP, nj = n - ni * NHP;
        v = ldE(x, (long)c * (HIMG * WIMG) + (5 * ni + ki) * WIMG + 5 * nj + li, md);
      }
      As[q][p] = v;
    }
    for (int e = tid; e < 1600; e += 256) {
      int o = e / 25, q = e - o * 25;
      Bs[q][o] = ldE(w, (long)(n0 + o) * 6400 + c * 25 + q, md);
    }
    __syncthreads();
#pragma unroll
    for (int kk = 0; kk < 25; ++kk) {
      float4 av = *(const float4*)&As[kk][tr * 4];
      float4 bv = *(const float4*)&Bs[kk][tc * 4];
      float a[4] = {av.x, av.y, av.z, av.w};
      float b[4] = {bv.x, bv.y, bv.z, bv.w};
#pragma unroll
      for (int i = 0; i < 4; ++i)
#pragma unroll
        for (int j = 0; j < 4; ++j) acc[i][j] = fmaf(a[i], b[j], acc[i][j]);
    }
  }
#pragma unroll
  for (int i = 0; i < 4; ++i) {
    int row = m0 + tr * 4 + i;
    if (row < NN) {
#pragma unroll
      for (int j = 0; j < 4; ++j)
        part[((size_t)z * NN + row) * 256 + n0 + tc * 4 + j] = acc[i][j];
    }
  }
}

// ============ adj = emb@emb.T row top-7, column-split ============
__global__ __launch_bounds__(256) void adj_part(
    const float* __restrict__ emb, float* __restrict__ cv, int* __restrict__ ci) {
  __shared__ float rc[16][260];
  __shared__ float mv[16][112];
  __shared__ int mi[16][112];
  const int r0 = blockIdx.x * 16;
  const int cs = blockIdx.y;
  const int tid = threadIdx.x;
  for (int e = tid; e < 16 * 256; e += 256) {
    int rr = e >> 8, cc = e & 255;
    rc[rr][cc] = emb[(size_t)(r0 + rr) * 256 + cc];
  }
  __syncthreads();
  const int tr = tid & 15, tc = tid >> 4;
  float bv[7];
  int bi[7];
#pragma unroll
  for (int k = 0; k < 7; ++k) { bv[k] = -1e38f; bi[k] = 0x7fffffff; }

  const float4* rp4 = (const float4*)(&rc[tr][0]);
  const int cend = cs * 900 + 900;
  for (int c = cs * 900 + tc; c < cend; c += 16) {
    const float4* ep = (const float4*)(emb + (size_t)c * 256);
    float4 s = make_float4(0.f, 0.f, 0.f, 0.f);
#pragma unroll 8
    for (int i = 0; i < 64; ++i) {
      float4 e4 = ep[i];
      float4 r4 = rp4[i];
      s.x = fmaf(r4.x, e4.x, s.x);
      s.y = fmaf(r4.y, e4.y, s.y);
      s.z = fmaf(r4.z, e4.z, s.z);
      s.w = fmaf(r4.w, e4.w, s.w);
    }
    float dot = (s.x + s.y) + (s.z + s.w);
    if (dot > bv[6] || (dot == bv[6] && c < bi[6])) {
      int p = 6;
      while (p > 0 && (dot > bv[p - 1] || (dot == bv[p - 1] && c < bi[p - 1]))) {
        bv[p] = bv[p - 1]; bi[p] = bi[p - 1]; --p;
      }
      bv[p] = dot; bi[p] = c;
    }
  }
#pragma unroll
  for (int k = 0; k < 7; ++k) { mv[tr][tc * 7 + k] = bv[k]; mi[tr][tc * 7 + k] = bi[k]; }
  __syncthreads();
  if (tid < 16) {
    int row = r0 + tid;
    int ptr[16];
#pragma unroll
    for (int l = 0; l < 16; ++l) ptr[l] = 0;
    for (int k = 0; k < 7; ++k) {
      float best = -1e38f; int bidx = 0x7fffffff; int bl = 0;
      for (int l = 0; l < 16; ++l) {
        float v = mv[tid][l * 7 + ptr[l]];
        int ii = mi[tid][l * 7 + ptr[l]];
        if (v > best || (v == best && ii < bidx)) { best = v; bidx = ii; bl = l; }
      }
      ptr[bl]++;
      cv[((size_t)cs * NN + row) * 7 + k] = best;
      ci[((size_t)cs * NN + row) * 7 + k] = bidx;
    }
  }
}

__global__ __launch_bounds__(256) void adj_merge(
    const float* __restrict__ cv, const int* __restrict__ ci,
    int* __restrict__ idx_o, int* __restrict__ keep_o) {
  int row = blockIdx.x * 256 + threadIdx.x;
  if (row >= NN) return;
  int p[4] = {0, 0, 0, 0};
  for (int k = 0; k < 7; ++k) {
    float best = -1e38f; int bidx = 0x7fffffff; int bc = 0;
    for (int c = 0; c < 4; ++c) {
      float v = cv[((size_t)c * NN + row) * 7 + p[c]];
      int ii = ci[((size_t)c * NN + row) * 7 + p[c]];
      if (v > best || (v == best && ii < bidx)) { best = v; bidx = ii; bc = c; }
    }
    p[bc]++;
    idx_o[row * 7 + k] = bidx;
    keep_o[row * 7 + k] = (bidx > row && best != 0.0f) ? 1 : 0;
  }
}

// ---------------- spatial kNN via 5x5 window (provably identical to full scan) ----------------
__global__ __launch_bounds__(256) void spatial_topk(int* __restrict__ idx_o, int* __restrict__ keep_o) {
  int r = blockIdx.x * 256 + threadIdx.x;
  if (r >= NN) return;
  int ri = r / NHP, rj = r - (r / NHP) * NHP;
  int bd[7], bi[7];
#pragma unroll
  for (int k = 0; k < 7; ++k) { bd[k] = 0x7fffffff; bi[k] = 0x7fffffff; }
  int ilo = ri - 2 > 0 ? ri - 2 : 0, ihi = ri + 2 < NHP - 1 ? ri + 2 : NHP - 1;
  int jlo = rj - 2 > 0 ? rj - 2 : 0, jhi = rj + 2 < NHP - 1 ? rj + 2 : NHP - 1;
  for (int i2 = ilo; i2 <= ihi; ++i2) {
    int dy = ri - i2; int dy2 = dy * dy;
    for (int j2 = jlo; j2 <= jhi; ++j2) {
      int dx = rj - j2;
      int d = dy2 + dx * dx;
      int m = i2 * NHP + j2;
      if (d < bd[6]) {
        int pq = 6;
        while (pq > 0 && d < bd[pq - 1]) { bd[pq] = bd[pq - 1]; bi[pq] = bi[pq - 1]; --pq; }
        bd[pq] = d; bi[pq] = m;
      }
    }
  }
#pragma unroll
  for (int k = 0; k < 7; ++k) {
    idx_o[r * 7 + k] = bi[k];
    keep_o[r * 7 + k] = (bi[k] >= r && bd[k] != 0) ? 1 : 0;
  }
}

// ---------------- GATv2 aggregation, single head (stride 256) ----------------
__global__ __launch_bounds__(256) void gat_agg1(
    const float* __restrict__ xl, const float* __restrict__ xr,
    const void* __restrict__ att, long attoff, const void* __restrict__ gbias, long gboff,
    const int* __restrict__ nbr, const int* __restrict__ keep,
    float* __restrict__ out, const int* __restrict__ mode) {
  const int md = *mode;
  const int r = blockIdx.x;
  const int f = threadIdx.x;
  __shared__ int s_src[8];
  __shared__ int s_mask_s;
  __shared__ float red[4][8];
  if (f < 7) {
    int v = nbr[r * 7 + f];
    s_src[f] = ((unsigned)v < (unsigned)NN) ? v : 0;
  }
  if (f == 7) s_src[7] = r;
  if (f == 0) {
    int mk = 0x80;
    for (int e = 0; e < 7; ++e)
      if (keep[r * 7 + e] != 0) mk |= (1 << e);
    s_mask_s = mk;
  }
  __syncthreads();
  const int mask = s_mask_s;
  const int wid = f >> 6, lane = f & 63;

  float xrv = xr[(size_t)r * 256 + f];
  float attv = ldE(att, attoff + f, md);
  float xlv[8], part[8];
#pragma unroll
  for (int e = 0; e < 8; ++e) {
    xlv[e] = 0.f; part[e] = 0.f;
    if (mask & (1 << e)) {
      float v = xl[(size_t)s_src[e] * 256 + f];
      xlv[e] = v;
      float s = v + xrv;
      s = s > 0.f ? s : 0.2f * s;
      part[e] = s * attv;
    }
  }
#pragma unroll
  for (int e = 0; e < 8; ++e) {
    float v = part[e];
#pragma unroll
    for (int off = 32; off > 0; off >>= 1) v += __shfl_xor(v, off, 64);
    if (lane == 0) red[wid][e] = v;
  }
  __syncthreads();
  float m = -1e38f;
  float logit[8];
#pragma unroll
  for (int e = 0; e < 8; ++e) {
    logit[e] = red[0][e] + red[1][e] + red[2][e] + red[3][e];
    if (mask & (1 << e)) m = fmaxf(m, logit[e]);
  }
  float den = 0.f, al[8];
#pragma unroll
  for (int e = 0; e < 8; ++e) {
    al[e] = (mask & (1 << e)) ? expf(logit[e] - m) : 0.f;
    den += al[e];
  }
  float inv = 1.0f / den;
  float o = 0.f;
#pragma unroll
  for (int e = 0; e < 8; ++e) o = fmaf(al[e], xlv[e], o);
  o = o * inv + ldE(gbias, gboff + f, md);
  o = o > 0.f ? o : expm1f(o);
  out[(size_t)r * 256 + f] = o;
}

// ---------------- GATv2 aggregation, 8 heads (stride 2048, wide path) ----------------
__global__ __launch_bounds__(256) void gat_agg8(
    const float* __restrict__ xl, const float* __restrict__ xr,
    const void* __restrict__ att, const void* __restrict__ gbias,
    const int* __restrict__ nbr, const int* __restrict__ keep,
    float* __restrict__ out, const int* __restrict__ mode) {
  const int md = *mode;
  const int r = blockIdx.x;
  const int f = threadIdx.x;
  __shared__ int s_src[8];
  __shared__ int s_mask_s;
  __shared__ float red[4][8];
  if (f < 7) {
    int v = nbr[r * 7 + f];
    s_src[f] = ((unsigned)v < (unsigned)NN) ? v : 0;
  }
  if (f == 7) s_src[7] = r;
  if (f == 0) {
    int mk = 0x80;
    for (int e = 0; e < 7; ++e)
      if (keep[r * 7 + e] != 0) mk |= (1 << e);
    s_mask_s = mk;
  }
  __syncthreads();
  const int mask = s_mask_s;
  const int wid = f >> 6, lane = f & 63;

  for (int h = 0; h < 8; ++h) {
    float xrv = xr[(size_t)r * 2048 + h * 256 + f];
    float attv = ldE(att, h * 256 + f, md);
    float xlv[8], part[8];
#pragma unroll
    for (int e = 0; e < 8; ++e) {
      xlv[e] = 0.f; part[e] = 0.f;
      if (mask & (1 << e)) {
        float v = xl[(size_t)s_src[e] * 2048 + h * 256 + f];
        xlv[e] = v;
        float s = v + xrv;
        s = s > 0.f ? s : 0.2f * s;
        part[e] = s * attv;
      }
    }
#pragma unroll
    for (int e = 0; e < 8; ++e) {
      float v = part[e];
#pragma unroll
      for (int off = 32; off > 0; off >>= 1) v += __shfl_xor(v, off, 64);
      if (lane == 0) red[wid][e] = v;
    }
    __syncthreads();
    float m = -1e38f;
    float logit[8];
#pragma unroll
    for (int e = 0; e < 8; ++e) {
      logit[e] = red[0][e] + red[1][e] + red[2][e] + red[3][e];
      if (mask & (1 << e)) m = fmaxf(m, logit[e]);
    }
    float den = 0.f, al[8];
#pragma unroll
    for (int e = 0; e < 8; ++e) {
      al[e] = (mask & (1 << e)) ? expf(logit[e] - m) : 0.f;
      den += al[e];
    }
    float inv = 1.0f / den;
    float o = 0.f;
#pragma unroll
    for (int e = 0; e < 8; ++e) o = fmaf(al[e], xlv[e], o);
    o = o * inv + ldE(gbias, h * 256 + f, md);
    o = o > 0.f ? o : expm1f(o);
    out[(size_t)r * 2048 + h * 256 + f] = o;
    __syncthreads();
  }
}

// ---------------- final: out = relu(cat(h2,h4)@fc3 + b) + h4 ----------------
__global__ __launch_bounds__(256) void fc3_final(
    const float* __restrict__ h2, const float* __restrict__ h4,
    const void* __restrict__ B, const void* __restrict__ bias,
    void* __restrict__ outp, const int* __restrict__ mode) {
  const int md = *mode;
  __shared__ float As[16][68];
  __shared__ float Bs[16][68];
  const int m0 = blockIdx.y * 64, n0 = blockIdx.x * 64;
  const int tid = threadIdx.x;
  const int tr = tid >> 4, tc = tid & 15;
  const int ar = tid >> 2, akq = tid & 3;
  const int bkr = tid >> 4, bnc = tid & 15;
  const int arow = m0 + ar;
  float acc[4][4] = {};

  for (int k0 = 0; k0 < 512; k0 += 16) {
    __syncthreads();
    {
      int k = k0 + akq * 4;
      float4 v = make_float4(0.f, 0.f, 0.f, 0.f);
      if (arow < NN) {
        const float* src = (k < 256) ? (h2 + (size_t)arow * 256 + k)
                                     : (h4 + (size_t)arow * 256 + (k - 256));
        v = *(const float4*)src;
      }
      As[akq * 4 + 0][ar] = v.x;
      As[akq * 4 + 1][ar] = v.y;
      As[akq * 4 + 2][ar] = v.z;
      As[akq * 4 + 3][ar] = v.w;
    }
    {
      long bidx = (long)(k0 + bkr) * 256 + n0 + bnc * 4;
      if (md) {
        ushort4 u = *(const ushort4*)((const unsigned short*)B + bidx);
        Bs[bkr][bnc * 4 + 0] = bf2f(u.x);
        Bs[bkr][bnc * 4 + 1] = bf2f(u.y);
        Bs[bkr][bnc * 4 + 2] = bf2f(u.z);
        Bs[bkr][bnc * 4 + 3] = bf2f(u.w);
      } else {
        float4 v = *(const float4*)((const float*)B + bidx);
        Bs[bkr][bnc * 4 + 0] = v.x;
        Bs[bkr][bnc * 4 + 1] = v.y;
        Bs[bkr][bnc * 4 + 2] = v.z;
        Bs[bkr][bnc * 4 + 3] = v.w;
      }
    }
    __syncthreads();
#pragma unroll
    for (int kk = 0; kk < 16; ++kk) {
      float4 av = *(const float4*)&As[kk][tr * 4];
      float4 bv = *(const float4*)&Bs[kk][tc * 4];
      float a[4] = {av.x, av.y, av.z, av.w};
      float b[4] = {bv.x, bv.y, bv.z, bv.w};
#pragma unroll
      for (int i = 0; i < 4; ++i)
#pragma unroll
        for (int j = 0; j < 4; ++j) acc[i][j] = fmaf(a[i], b[j], acc[i][j]);
    }
  }
#pragma unroll
  for (int i = 0; i < 4; ++i) {
    int row = m0 + tr * 4 + i;
    if (row < NN) {
#pragma unroll
      for (int j = 0; j < 4; ++j) {
        int col = n0 + tc * 4 + j;
        float v = fmaxf(acc[i][j] + ldE(bias, col, md), 0.f) + h4[(size_t)row * 256 + col];
        if (md) ((__hip_bfloat16*)outp)[(size_t)row * 256 + col] = __float2bfloat16(v);
        else ((float*)outp)[(size_t)row * 256 + col] = v;
      }
    }
  }
}

// ---------------- launcher ----------------
extern "C" void kernel_launch(void* const* d_in, const int* in_sizes, int n_in,
                              void* d_out, int out_size, void* d_ws, size_t ws_size,
                              hipStream_t stream) {
  (void)in_sizes; (void)n_in; (void)out_size;
  const void* x    = d_in[0];
  const void* w1   = d_in[1];
  const void* b1   = d_in[2];
  const void* fc2w = d_in[3];
  const void* fc2b = d_in[4];
  const void* fc3w = d_in[5];
  const void* fc3b = d_in[6];
  const void* g_wl[4]   = {d_in[7],  d_in[13], d_in[19], d_in[25]};
  const void* g_bl[4]   = {d_in[8],  d_in[14], d_in[20], d_in[26]};
  const void* g_wr[4]   = {d_in[9],  d_in[15], d_in[21], d_in[27]};
  const void* g_br[4]   = {d_in[10], d_in[16], d_in[22], d_in[28]};
  const void* g_att[4]  = {d_in[11], d_in[17], d_in[23], d_in[29]};
  const void* g_bias[4] = {d_in[12], d_in[18], d_in[24], d_in[30]};

  float* ws = (float*)d_ws;
  int* mode = (int*)d_ws;
  size_t off = 64;
  float* emb = ws + off; off += (size_t)NN * 256;
  float* xl2 = ws + off; off += (size_t)NN * 256;
  float* xr2 = ws + off; off += (size_t)NN * 256;
  float* h2  = ws + off; off += (size_t)NN * 256;
  float* h4  = ws + off; off += (size_t)NN * 256;
  int* idx1  = (int*)(ws + off); off += NN * 7;
  int* keep1 = (int*)(ws + off); off += NN * 7;
  int* idx2  = (int*)(ws + off); off += NN * 7;
  int* keep2 = (int*)(ws + off); off += NN * 7;
  float* scratch = ws + off;
  const size_t wide_need = off + 3 * (size_t)NN * 2048;          // 107.3 MB
  const bool wide = ws_size >= wide_need * sizeof(float);
  // narrow footprint = off + 3*NN*256 = exactly round-3's proven 29.9 MB

  float* emb1 = h2;            // conv output; dead before h2 is written
  float* cv = scratch;         // adj partials (sequenced after conv partials die)
  int* ci = (int*)(scratch + 4 * (size_t)NN * 7);

  dim3 blk(256);
  const int* idxs[2]  = {idx1, idx2};
  const int* keeps[2] = {keep1, keep2};
  float* houts[2] = {h2, h4};

  detect_mode<<<dim3(1), blk, 0, stream>>>((const unsigned short*)x, mode);

  // conv1: channel-split partials into scratch, then reduce(+bias+relu) -> emb1
  const int convKS = wide ? 8 : 2;
  patch_part<<<dim3(4, 57, convKS), blk, 0, stream>>>(x, w1, scratch, 256 / convKS, mode);
  reduce_u<1><<<dim3(1024, 1, 1), blk, 0, stream>>>(scratch, convKS, NN, 256,
                                                    b1, b1, 0, emb1, emb1, 256, mode);
  // fc2 -> emb
  gemm_u<0, 1><<<dim3(4, 57, 1), blk, 0, stream>>>(emb1, fc2w, fc2w, 0, fc2b, fc2b, 0,
                                                   emb, emb, nullptr, 256,
                                                   NN, 256, 256, 1, 256, mode);
  // graphs
  adj_part<<<dim3(225, 4), blk, 0, stream>>>(emb, cv, ci);
  adj_merge<<<dim3(15), blk, 0, stream>>>(cv, ci, idx1, keep1);
  spatial_topk<<<dim3(15), blk, 0, stream>>>(idx2, keep2);

  if (wide) {
    float* xl_w = scratch;
    float* xr_w = xl_w + (size_t)NN * 2048;
    float* hh_w = xr_w + (size_t)NN * 2048;
    float* g24part = scratch;  // aliases xl_w (dead once hh_w is built)

    for (int g = 0; g < 2; ++g) {
      int a = g * 2, b = g * 2 + 1;
      gemm_u<0, 0><<<dim3(32, 57, 2), blk, 0, stream>>>(emb, g_wl[a], g_wr[a], 0,
                                                        g_bl[a], g_br[a], 0,
                                                        xl_w, xr_w, nullptr, 2048,
                                                        NN, 256, 256, 1, 2048, mode);
      gat_agg8<<<dim3(NN), blk, 0, stream>>>(xl_w, xr_w, g_att[a], g_bias[a],
                                             idxs[g], keeps[g], hh_w, mode);
      gemm_u<2, 0><<<dim3(4, 57, 8), blk, 0, stream>>>(hh_w, g_wl[b], g_wr[b], 0,
                                                       g_bl[b], g_br[b], 0,
                                                       nullptr, nullptr, g24part, 256,
                                                       NN, 2048, 512, 4, 256, mode);
      reduce_u<0><<<dim3(1024, 1, 2), blk, 0, stream>>>(g24part, 4, NN, 256,
                                                        g_bl[b], g_br[b], 0,
                                                        xl2, xr2, 256, mode);
      gat_agg1<<<dim3(NN), blk, 0, stream>>>(xl2, xr2, g_att[b], 0, g_bias[b], 0,
                                             idxs[g], keeps[g], houts[g], mode);
    }
  } else {
    float* xlh = scratch;
    float* xrh = xlh + (size_t)NN * 256;
    float* hh  = xrh + (size_t)NN * 256;

    for (int g = 0; g < 2; ++g) {
      int a = g * 2, b = g * 2 + 1;
      for (int h = 0; h < 8; ++h) {
        gemm_u<0, 0><<<dim3(4, 57, 2), blk, 0, stream>>>(emb, g_wl[a], g_wr[a], h * 256,
                                                         g_bl[a], g_br[a], h * 256,
                                                         xlh, xrh, nullptr, 256,
                                                         NN, 256, 256, 1, 2048, mode);
        gat_agg1<<<dim3(NN), blk, 0, stream>>>(xlh, xrh, g_att[a], h * 256, g_bias[a], h * 256,
                                               idxs[g], keeps[g], hh, mode);
        if (h == 0) {
          gemm_u<0, 0><<<dim3(4, 57, 2), blk, 0, stream>>>(hh, g_wl[b], g_wr[b], 0,
                                                           g_bl[b], g_br[b], 0,
                                                           xl2, xr2, nullptr, 256,
                                                           NN, 256, 256, 1, 256, mode);
        } else {
          gemm_u<1, 0><<<dim3(4, 57, 2), blk, 0, stream>>>(hh, g_wl[b], g_wr[b], (long)h * 256 * 256,
                                                           g_bl[b], g_br[b], 0,
                                                           xl2, xr2, nullptr, 256,
                                                           NN, 256, 256, 1, 256, mode);
        }
      }
      gat_agg1<<<dim3(NN), blk, 0, stream>>>(xl2, xr2, g_att[b], 0, g_bias[b], 0,
                                             idxs[g], keeps[g], houts[g], mode);
    }
  }

  fc3_final<<<dim3(4, 57), blk, 0, stream>>>(h2, h4, fc3w, fc3b, d_out, mode);
}